// Round 1
// baseline (5856.079 us; speedup 1.0000x reference)
//
#include <hip/hip_runtime.h>

// Problem constants (fixed by the reference setup_inputs()).
#define S_     4
#define E_     8
#define NPS    12500        // atoms per species (N/S)
#define AEVD   1008
#define D1     256
#define D2     192
#define D3     160
#define TM     32           // atoms per tile
#define NTILES ((NPS + TM - 1) / TM)   // 391
#define ALPHA  0.1f

__device__ __forceinline__ float celu_f(float v) {
    return v > 0.0f ? v : ALPHA * (__expf(v * (1.0f / ALPHA)) - 1.0f);
}

// LDS plan (bytes):
//   H1s [32][257] = 32896   (phase1-2; aliased as H3s [32][161] in phase3-4)
//   H2s [32][193] = 24704   (phase2-3)
//   C   [4640]    = 18560   scratch: phase1 Xs[32][17]+Ws[16][256];
//                           phase2 Wc2[16][192]; phase3 Wc3[16][160]; phase4 row sums
// total = 76160 B -> 2 blocks/CU.
__global__ __launch_bounds__(256, 2)
void ani_fused(const float* __restrict__ aev,
               const int*   __restrict__ idx,
               const float* __restrict__ W1, const float* __restrict__ b1,
               const float* __restrict__ W2, const float* __restrict__ b2,
               const float* __restrict__ W3, const float* __restrict__ b3,
               const float* __restrict__ W4, const float* __restrict__ b4,
               float* __restrict__ partials)
{
    const int tile = blockIdx.x;
    const int s    = blockIdx.y;
    const int e    = blockIdx.z;
    const int t    = threadIdx.x;
    const int se   = s * E_ + e;

    __shared__ float H1s[TM][D1 + 1];          // 32 x 257
    __shared__ float H2s[TM][D2 + 1];          // 32 x 193
    __shared__ __align__(16) float C[TM * 17 + 16 * D1];   // 4640 floats

    float* Xs  = C;                 // [32][17]
    float* Ws  = C + TM * 17;       // [16][256], 16B-aligned (544*4 = 2176)
    float* H3s = &H1s[0][0];        // [32][161] alias (phase 3+)

    // ---------------- Phase 1: H1 = celu(X @ W1 + b1), K = 1008 ----------------
    const int rg = t >> 5;          // 0..7  -> rows rg*4 .. rg*4+3
    const int cg = t & 31;          // 0..31 -> cols cg*8 .. cg*8+7

    // X staging map: 512 elems/chunk; thread loads rows (t>>4) and (t>>4)+16 at k=(t&15)
    const int arow0 = tile * TM + (t >> 4);
    const int arow1 = arow0 + 16;
    const int ga0 = idx[s * NPS + (arow0 < NPS ? arow0 : NPS - 1)];
    const int ga1 = idx[s * NPS + (arow1 < NPS ? arow1 : NPS - 1)];
    const float* aev0 = aev + (size_t)ga0 * AEVD + (t & 15);
    const float* aev1 = aev + (size_t)ga1 * AEVD + (t & 15);
    const int xsi0 = (t >> 4) * 17 + (t & 15);
    const int xsi1 = xsi0 + 16 * 17;

    const float* w1p = W1 + (size_t)se * AEVD * D1;

    float acc[4][8];
    #pragma unroll
    for (int r = 0; r < 4; ++r)
        #pragma unroll
        for (int c = 0; c < 8; ++c) acc[r][c] = 0.0f;

    for (int kb = 0; kb < AEVD / 16; ++kb) {   // 63 chunks
        __syncthreads();
        // stage X chunk
        Xs[xsi0] = aev0[kb * 16];
        Xs[xsi1] = aev1[kb * 16];
        // stage W chunk: contiguous 16*256 floats, float4-coalesced
        const float4* wsrc = (const float4*)(w1p + (size_t)kb * 16 * D1);
        float4* wdst = (float4*)Ws;
        #pragma unroll
        for (int i = 0; i < 4; ++i) wdst[i * 256 + t] = wsrc[i * 256 + t];
        __syncthreads();
        #pragma unroll
        for (int k = 0; k < 16; ++k) {
            float xr[4];
            #pragma unroll
            for (int r = 0; r < 4; ++r) xr[r] = Xs[(rg * 4 + r) * 17 + k];
            const float* wrow = Ws + k * D1 + cg * 8;
            float wv[8];
            #pragma unroll
            for (int c = 0; c < 8; ++c) wv[c] = wrow[c];
            #pragma unroll
            for (int r = 0; r < 4; ++r)
                #pragma unroll
                for (int c = 0; c < 8; ++c) acc[r][c] += xr[r] * wv[c];
        }
    }
    {
        const float* b1p = b1 + (size_t)se * D1 + cg * 8;
        float bv[8];
        #pragma unroll
        for (int c = 0; c < 8; ++c) bv[c] = b1p[c];
        #pragma unroll
        for (int r = 0; r < 4; ++r)
            #pragma unroll
            for (int c = 0; c < 8; ++c)
                H1s[rg * 4 + r][cg * 8 + c] = celu_f(acc[r][c] + bv[c]);
    }

    // ---------------- Phase 2: H2 = celu(H1 @ W2 + b2), K = 256 ----------------
    const float* w2p = W2 + (size_t)se * D1 * D2;
    float acc2[4][6];
    #pragma unroll
    for (int r = 0; r < 4; ++r)
        #pragma unroll
        for (int c = 0; c < 6; ++c) acc2[r][c] = 0.0f;

    for (int kb = 0; kb < D1 / 16; ++kb) {     // 16 chunks
        __syncthreads();
        // stage 16x192 = 3072 floats = 768 float4 -> 3/thread
        const float4* src = (const float4*)(w2p + (size_t)kb * 16 * D2);
        float4* dst = (float4*)C;
        #pragma unroll
        for (int i = 0; i < 3; ++i) dst[i * 256 + t] = src[i * 256 + t];
        __syncthreads();
        #pragma unroll
        for (int k = 0; k < 16; ++k) {
            float xr[4];
            #pragma unroll
            for (int r = 0; r < 4; ++r) xr[r] = H1s[rg * 4 + r][kb * 16 + k];
            const float* wrow = C + k * D2 + cg * 6;
            float wv[6];
            #pragma unroll
            for (int c = 0; c < 6; ++c) wv[c] = wrow[c];
            #pragma unroll
            for (int r = 0; r < 4; ++r)
                #pragma unroll
                for (int c = 0; c < 6; ++c) acc2[r][c] += xr[r] * wv[c];
        }
    }
    __syncthreads();   // all reads of H1s done before H2s... (H2s separate; sync guards C reuse ordering below anyway)
    {
        const float* b2p = b2 + (size_t)se * D2 + cg * 6;
        #pragma unroll
        for (int r = 0; r < 4; ++r)
            #pragma unroll
            for (int c = 0; c < 6; ++c)
                H2s[rg * 4 + r][cg * 6 + c] = celu_f(acc2[r][c] + b2p[c]);
    }

    // ---------------- Phase 3: H3 = celu(H2 @ W3 + b3), K = 192 ----------------
    const float* w3p = W3 + (size_t)se * D2 * D3;
    float acc3[4][5];
    #pragma unroll
    for (int r = 0; r < 4; ++r)
        #pragma unroll
        for (int c = 0; c < 5; ++c) acc3[r][c] = 0.0f;

    for (int kb = 0; kb < D2 / 16; ++kb) {     // 12 chunks
        __syncthreads();
        // stage 16x160 = 2560 floats = 640 float4
        const float4* src = (const float4*)(w3p + (size_t)kb * 16 * D3);
        float4* dst = (float4*)C;
        #pragma unroll
        for (int i = 0; i < 3; ++i) {
            int j = i * 256 + t;
            if (j < 640) dst[j] = src[j];
        }
        __syncthreads();
        #pragma unroll
        for (int k = 0; k < 16; ++k) {
            float xr[4];
            #pragma unroll
            for (int r = 0; r < 4; ++r) xr[r] = H2s[rg * 4 + r][kb * 16 + k];
            const float* wrow = C + k * D3 + cg * 5;
            float wv[5];
            #pragma unroll
            for (int c = 0; c < 5; ++c) wv[c] = wrow[c];
            #pragma unroll
            for (int r = 0; r < 4; ++r)
                #pragma unroll
                for (int c = 0; c < 5; ++c) acc3[r][c] += xr[r] * wv[c];
        }
    }
    {
        const float* b3p = b3 + (size_t)se * D3 + cg * 5;
        #pragma unroll
        for (int r = 0; r < 4; ++r)
            #pragma unroll
            for (int c = 0; c < 5; ++c)
                H3s[(rg * 4 + r) * (D3 + 1) + cg * 5 + c] = celu_f(acc3[r][c] + b3p[c]);
    }
    __syncthreads();

    // ---------------- Phase 4: out = H3 @ W4 + b4, block reduce ----------------
    const float* w4p = W4 + (size_t)se * D3;
    const float  b4v = b4[se];
    const int row = t >> 3;
    const int seg = t & 7;
    float sum = 0.0f;
    #pragma unroll
    for (int j = 0; j < 20; ++j) {
        int k = seg * 20 + j;
        sum += H3s[row * (D3 + 1) + k] * w4p[k];
    }
    sum += __shfl_xor(sum, 1);
    sum += __shfl_xor(sum, 2);
    sum += __shfl_xor(sum, 4);
    float rowval = (tile * TM + row < NPS) ? (sum + b4v) : 0.0f;
    if (seg == 0) C[row] = rowval;     // C reads all done (sync above)
    __syncthreads();
    if (t == 0) {
        float tot = 0.0f;
        #pragma unroll
        for (int r = 0; r < TM; ++r) tot += C[r];
        partials[tile + NTILES * (s + S_ * e)] = tot;
    }
}

__global__ void reduce_partials(const float* __restrict__ p, int n, float* __restrict__ out)
{
    float s = 0.0f;
    for (int i = threadIdx.x; i < n; i += 256) s += p[i];
    #pragma unroll
    for (int o = 32; o > 0; o >>= 1) s += __shfl_xor(s, o);
    __shared__ float sm[4];
    if ((threadIdx.x & 63) == 0) sm[threadIdx.x >> 6] = s;
    __syncthreads();
    if (threadIdx.x == 0) {
        float tot = sm[0] + sm[1] + sm[2] + sm[3];
        out[0] = tot * (1.0f / E_);
    }
}

extern "C" void kernel_launch(void* const* d_in, const int* in_sizes, int n_in,
                              void* d_out, int out_size, void* d_ws, size_t ws_size,
                              hipStream_t stream)
{
    // setup_inputs() dict order: aev, species, idx, W1,b1, W2,b2, W3,b3, W4,b4
    const float* aev = (const float*)d_in[0];
    const int*   idx = (const int*)  d_in[2];
    const float* W1  = (const float*)d_in[3];
    const float* b1  = (const float*)d_in[4];
    const float* W2  = (const float*)d_in[5];
    const float* b2  = (const float*)d_in[6];
    const float* W3  = (const float*)d_in[7];
    const float* b3  = (const float*)d_in[8];
    const float* W4  = (const float*)d_in[9];
    const float* b4  = (const float*)d_in[10];
    float* out      = (float*)d_out;
    float* partials = (float*)d_ws;   // NTILES*S_*E_ floats = ~50 KB

    dim3 grid(NTILES, S_, E_);
    ani_fused<<<grid, 256, 0, stream>>>(aev, idx, W1, b1, W2, b2, W3, b3, W4, b4, partials);
    reduce_partials<<<1, 256, 0, stream>>>(partials, NTILES * S_ * E_, out);
}

// Round 2
// 959.347 us; speedup vs baseline: 6.1042x; 6.1042x over previous
//
#include <hip/hip_runtime.h>

#define S_    4
#define E_    8
#define NPS   12500
#define AEVD  1008
#define D1    256
#define D2    192
#define D3    160
#define TM    64
#define NT    ((NPS + TM - 1) / TM)    // 196
#define ALPHA 0.1f

// packed-weight geometry: [kb][nb][lane(64)][8] bf16, K padded to kb*32
#define KB1 32
#define NB1 16
#define KB2 8
#define NB2 12
#define KB3 6
#define NB3 10

typedef __attribute__((ext_vector_type(8))) short short8;
typedef __attribute__((ext_vector_type(4))) float f32x4;

__device__ __forceinline__ ushort f2bf(float f) {
    unsigned u = __float_as_uint(f);
    unsigned r = u + 0x7FFFu + ((u >> 16) & 1u);   // RNE
    return (ushort)(r >> 16);
}
__device__ __forceinline__ float bf2f(ushort u) {
    return __uint_as_float(((unsigned)u) << 16);
}
__device__ __forceinline__ float celu_f(float v) {
    return v > 0.0f ? v : ALPHA * (__expf(v * (1.0f / ALPHA)) - 1.0f);
}

#define GLDS16(gp, lp) \
    __builtin_amdgcn_global_load_lds((const __attribute__((address_space(1))) void*)(gp), \
                                     (__attribute__((address_space(3))) void*)(lp), 16, 0, 0)

// ---------------- weight pre-pack: fp32 [se][K][N] -> bf16 B-fragment order ----------------
__global__ void pack_w(const float* __restrict__ W, ushort* __restrict__ out,
                       int Ksrc, int kbs, int nbs, int Nsrc)
{
    const int b  = blockIdx.x;
    const int kb = b % kbs;
    const int se = b / kbs;
    const int t  = threadIdx.x;
    const int l  = t & 63, q = t >> 6;
    const float* Wse = W + (size_t)se * Ksrc * Nsrc;
    for (int i = 0; i < 4; ++i) {
        int nb = q + i * 4;
        if (nb >= nbs) break;
        int n = nb * 16 + (l & 15);
        ushort v[8];
        #pragma unroll
        for (int j = 0; j < 8; ++j) {
            int k = kb * 32 + ((l >> 4) << 3) + j;
            float x = (k < Ksrc) ? Wse[(size_t)k * Nsrc + n] : 0.0f;
            v[j] = f2bf(x);
        }
        uint4 u;
        u.x = (unsigned)v[0] | ((unsigned)v[1] << 16);
        u.y = (unsigned)v[2] | ((unsigned)v[3] << 16);
        u.z = (unsigned)v[4] | ((unsigned)v[5] << 16);
        u.w = (unsigned)v[6] | ((unsigned)v[7] << 16);
        *(uint4*)(out + ((((size_t)se * kbs + kb) * nbs + nb) * 64 + l) * 8) = u;
    }
}

// ---------------- fused 4-layer MFMA kernel ----------------
// block: 64 atoms x one (s,e); 4 waves, wave w owns rows w*16..w*16+15.
__global__ __launch_bounds__(256, 2)
void ani_mfma(const float* __restrict__ aev, const int* __restrict__ idx,
              const ushort* __restrict__ W1p, const ushort* __restrict__ W2p,
              const ushort* __restrict__ W3p,
              const float* __restrict__ b1, const float* __restrict__ b2,
              const float* __restrict__ b3,
              const float* __restrict__ W4, const float* __restrict__ b4,
              float* __restrict__ partials)
{
    const int se   = blockIdx.x;        // 0..31 (fastest -> aev tile reuse in L2/L3)
    const int tile = blockIdx.y;        // 0..195
    const int s    = se >> 3;
    const int t    = threadIdx.x;
    const int w    = t >> 6, l = t & 63;
    const int lm   = l & 15, kq = l >> 4;

    __shared__ ushort Blds[NB1 * 512];      // 16 KB B-staging (reused per layer; floats in phase 4)
    __shared__ ushort H1s[TM][D1 + 8];      // 64 x 264 bf16 (aliased as H3s later)
    __shared__ ushort H2s[TM][D2 + 8];      // 64 x 200 bf16

    // gathered aev row for this lane's A-fragment row
    const int ar  = tile * TM + w * 16 + lm;
    const int arc = ar < NPS ? ar : NPS - 1;
    const float* arow = aev + (size_t)idx[s * NPS + arc] * AEVD;

    // ================= Layer 1: [64x1008] x [1008x256] =================
    const ushort* w1se = W1p + (size_t)se * (KB1 * NB1 * 512);
    f32x4 acc1[NB1];
    #pragma unroll
    for (int nb = 0; nb < NB1; ++nb) acc1[nb] = (f32x4){0.f, 0.f, 0.f, 0.f};

    for (int kb = 0; kb < KB1; ++kb) {
        // A fragment: 8 consecutive fp32 from own gathered row (clamp into row; pad covered by zero weights)
        int k0 = kb * 32 + kq * 8;
        int k0c = k0 < AEVD ? k0 : 0;
        float4 fa = *(const float4*)(arow + k0c);
        float4 fb = *(const float4*)(arow + k0c + 4);

        __syncthreads();                    // previous chunk's B reads done
        #pragma unroll
        for (int i = 0; i < 4; ++i) {
            int nb = w + i * 4;
            GLDS16(w1se + ((size_t)(kb * NB1 + nb) * 64 + l) * 8, &Blds[nb * 512]);
        }
        __syncthreads();                    // B staged (vmcnt drained by barrier)

        short8 af;
        af[0] = (short)f2bf(fa.x); af[1] = (short)f2bf(fa.y);
        af[2] = (short)f2bf(fa.z); af[3] = (short)f2bf(fa.w);
        af[4] = (short)f2bf(fb.x); af[5] = (short)f2bf(fb.y);
        af[6] = (short)f2bf(fb.z); af[7] = (short)f2bf(fb.w);

        #pragma unroll
        for (int nb = 0; nb < NB1; ++nb) {
            short8 bf = *(const short8*)&Blds[nb * 512 + l * 8];
            acc1[nb] = __builtin_amdgcn_mfma_f32_16x16x32_bf16(af, bf, acc1[nb], 0, 0, 0);
        }
    }
    // epilogue: bias + celu -> H1s row-major bf16 (C layout: col=lm, row=kq*4+r)
    #pragma unroll
    for (int nb = 0; nb < NB1; ++nb) {
        int n = nb * 16 + lm;
        float bias = b1[se * D1 + n];
        #pragma unroll
        for (int r = 0; r < 4; ++r)
            H1s[w * 16 + kq * 4 + r][n] = f2bf(celu_f(acc1[nb][r] + bias));
    }

    // ================= Layer 2: [64x256] x [256x192] =================
    const ushort* w2se = W2p + (size_t)se * (KB2 * NB2 * 512);
    f32x4 acc2[NB2];
    #pragma unroll
    for (int nb = 0; nb < NB2; ++nb) acc2[nb] = (f32x4){0.f, 0.f, 0.f, 0.f};

    for (int kb = 0; kb < KB2; ++kb) {
        __syncthreads();
        #pragma unroll
        for (int i = 0; i < 3; ++i) {
            int nb = w + i * 4;            // 12 tiles, 3 per wave
            GLDS16(w2se + ((size_t)(kb * NB2 + nb) * 64 + l) * 8, &Blds[nb * 512]);
        }
        __syncthreads();
        short8 af = *(const short8*)&H1s[w * 16 + lm][kb * 32 + kq * 8];  // own wave's rows
        #pragma unroll
        for (int nb = 0; nb < NB2; ++nb) {
            short8 bf = *(const short8*)&Blds[nb * 512 + l * 8];
            acc2[nb] = __builtin_amdgcn_mfma_f32_16x16x32_bf16(af, bf, acc2[nb], 0, 0, 0);
        }
    }
    #pragma unroll
    for (int nb = 0; nb < NB2; ++nb) {
        int n = nb * 16 + lm;
        float bias = b2[se * D2 + n];
        #pragma unroll
        for (int r = 0; r < 4; ++r)
            H2s[w * 16 + kq * 4 + r][n] = f2bf(celu_f(acc2[nb][r] + bias));
    }

    // ================= Layer 3: [64x192] x [192x160] =================
    const ushort* w3se = W3p + (size_t)se * (KB3 * NB3 * 512);
    ushort* H3s = &H1s[0][0];              // alias: [64][168] bf16 (H1s dead after L2)
    f32x4 acc3[NB3];
    #pragma unroll
    for (int nb = 0; nb < NB3; ++nb) acc3[nb] = (f32x4){0.f, 0.f, 0.f, 0.f};

    for (int kb = 0; kb < KB3; ++kb) {
        __syncthreads();
        #pragma unroll
        for (int i = 0; i < 3; ++i) {
            int nb = w + i * 4;            // 10 tiles: waves 0,1 do 3; waves 2,3 do 2
            if (nb < NB3)
                GLDS16(w3se + ((size_t)(kb * NB3 + nb) * 64 + l) * 8, &Blds[nb * 512]);
        }
        __syncthreads();
        short8 af = *(const short8*)&H2s[w * 16 + lm][kb * 32 + kq * 8];
        #pragma unroll
        for (int nb = 0; nb < NB3; ++nb) {
            short8 bf = *(const short8*)&Blds[nb * 512 + l * 8];
            acc3[nb] = __builtin_amdgcn_mfma_f32_16x16x32_bf16(af, bf, acc3[nb], 0, 0, 0);
        }
    }
    #pragma unroll
    for (int nb = 0; nb < NB3; ++nb) {
        int n = nb * 16 + lm;
        float bias = b3[se * D3 + n];
        #pragma unroll
        for (int r = 0; r < 4; ++r)
            H3s[(w * 16 + kq * 4 + r) * (D3 + 8) + n] = f2bf(celu_f(acc3[nb][r] + bias));
    }

    // ================= Layer 4 + block reduction =================
    __syncthreads();                        // H3s visible; Blds reads done
    float* Wf = (float*)Blds;               // W4 staged as fp32
    if (t < D3) Wf[t] = W4[se * D3 + t];
    __syncthreads();

    const int row = t >> 2, seg = t & 3;
    float sum = 0.0f;
    #pragma unroll
    for (int j = 0; j < 40; ++j) {
        int k = seg * 40 + j;
        sum += bf2f(H3s[row * (D3 + 8) + k]) * Wf[k];
    }
    sum += __shfl_xor(sum, 1);
    sum += __shfl_xor(sum, 2);
    float rowval = (tile * TM + row < NPS) ? (sum + b4[se]) : 0.0f;
    float* Rs = Wf + 256;
    if (seg == 0) Rs[row] = rowval;
    __syncthreads();
    if (t == 0) {
        float tot = 0.0f;
        #pragma unroll
        for (int r = 0; r < TM; ++r) tot += Rs[r];
        partials[tile * (S_ * E_) + se] = tot;
    }
}

__global__ void reduce_partials(const float* __restrict__ p, int n, float* __restrict__ out)
{
    float s = 0.0f;
    for (int i = threadIdx.x; i < n; i += 256) s += p[i];
    #pragma unroll
    for (int o = 32; o > 0; o >>= 1) s += __shfl_xor(s, o);
    __shared__ float sm[4];
    if ((threadIdx.x & 63) == 0) sm[threadIdx.x >> 6] = s;
    __syncthreads();
    if (threadIdx.x == 0) out[0] = (sm[0] + sm[1] + sm[2] + sm[3]) * (1.0f / E_);
}

extern "C" void kernel_launch(void* const* d_in, const int* in_sizes, int n_in,
                              void* d_out, int out_size, void* d_ws, size_t ws_size,
                              hipStream_t stream)
{
    // inputs: aev, species, idx, W1,b1, W2,b2, W3,b3, W4,b4
    const float* aev = (const float*)d_in[0];
    const int*   idx = (const int*)  d_in[2];
    const float* W1  = (const float*)d_in[3];
    const float* b1  = (const float*)d_in[4];
    const float* W2  = (const float*)d_in[5];
    const float* b2  = (const float*)d_in[6];
    const float* W3  = (const float*)d_in[7];
    const float* b3  = (const float*)d_in[8];
    const float* W4  = (const float*)d_in[9];
    const float* b4  = (const float*)d_in[10];
    float* out = (float*)d_out;

    // ws layout (bf16 packed weights + partials), ~21.9 MB total
    ushort* w1p = (ushort*)d_ws;                                   // 32*32*16*512
    ushort* w2p = w1p + (size_t)S_ * E_ * KB1 * NB1 * 512;         // 32*8*12*512
    ushort* w3p = w2p + (size_t)S_ * E_ * KB2 * NB2 * 512;         // 32*6*10*512
    float* partials = (float*)(w3p + (size_t)S_ * E_ * KB3 * NB3 * 512);

    pack_w<<<S_ * E_ * KB1, 256, 0, stream>>>(W1, w1p, AEVD, KB1, NB1, D1);
    pack_w<<<S_ * E_ * KB2, 256, 0, stream>>>(W2, w2p, D1,   KB2, NB2, D2);
    pack_w<<<S_ * E_ * KB3, 256, 0, stream>>>(W3, w3p, D2,   KB3, NB3, D3);

    dim3 grid(S_ * E_, NT);   // se fastest: 32 blocks per tile share aev rows in L2/L3
    ani_mfma<<<grid, 256, 0, stream>>>(aev, idx, w1p, w2p, w3p,
                                       b1, b2, b3, W4, b4, partials);
    reduce_partials<<<1, 256, 0, stream>>>(partials, NT * S_ * E_, out);
}

// Round 3
// 837.071 us; speedup vs baseline: 6.9959x; 1.1461x over previous
//
#include <hip/hip_runtime.h>

#define S_    4
#define E_    8
#define NPS   12500
#define AEVD  1008
#define D1    256
#define D2    192
#define D3    160
#define TM    64
#define NT    ((NPS + TM - 1) / TM)    // 196
#define ALPHA 0.1f

// packed-weight geometry: [kb][nb][lane(64)][8] bf16, K padded to kb*32
#define KB1 32
#define NB1 16
#define KB2 8
#define NB2 12
#define KB3 6
#define NB3 10

typedef __attribute__((ext_vector_type(8))) short short8;
typedef __attribute__((ext_vector_type(4))) float f32x4;

__device__ __forceinline__ ushort f2bf(float f) {
    unsigned u = __float_as_uint(f);
    unsigned r = u + 0x7FFFu + ((u >> 16) & 1u);   // RNE
    return (ushort)(r >> 16);
}
__device__ __forceinline__ float bf2f(ushort u) {
    return __uint_as_float(((unsigned)u) << 16);
}
__device__ __forceinline__ float celu_f(float v) {
    return v > 0.0f ? v : ALPHA * (__expf(v * (1.0f / ALPHA)) - 1.0f);
}

// ---------------- weight pre-pack: fp32 [se][K][N] -> bf16 B-fragment order ----------------
__global__ void pack_w(const float* __restrict__ W, ushort* __restrict__ out,
                       int Ksrc, int kbs, int nbs, int Nsrc)
{
    const int b  = blockIdx.x;
    const int kb = b % kbs;
    const int se = b / kbs;
    const int t  = threadIdx.x;
    const int l  = t & 63, q = t >> 6;
    const float* Wse = W + (size_t)se * Ksrc * Nsrc;
    for (int i = 0; i < 4; ++i) {
        int nb = q + i * 4;
        if (nb >= nbs) break;
        int n = nb * 16 + (l & 15);
        ushort v[8];
        #pragma unroll
        for (int j = 0; j < 8; ++j) {
            int k = kb * 32 + ((l >> 4) << 3) + j;
            float x = (k < Ksrc) ? Wse[(size_t)k * Nsrc + n] : 0.0f;
            v[j] = f2bf(x);
        }
        uint4 u;
        u.x = (unsigned)v[0] | ((unsigned)v[1] << 16);
        u.y = (unsigned)v[2] | ((unsigned)v[3] << 16);
        u.z = (unsigned)v[4] | ((unsigned)v[5] << 16);
        u.w = (unsigned)v[6] | ((unsigned)v[7] << 16);
        *(uint4*)(out + ((((size_t)se * kbs + kb) * nbs + nb) * 64 + l) * 8) = u;
    }
}

// ---------------- fused 4-layer MFMA kernel, n-split waves, register-resident B ----------------
// block: 64 atoms x one (s,e); wave w computes ALL 64 rows x its col-slice.
__global__ __launch_bounds__(256, 2)
void ani_mfma(const float* __restrict__ aev, const int* __restrict__ idx,
              const ushort* __restrict__ W1p, const ushort* __restrict__ W2p,
              const ushort* __restrict__ W3p,
              const float* __restrict__ b1, const float* __restrict__ b2,
              const float* __restrict__ b3,
              const float* __restrict__ W4, const float* __restrict__ b4,
              float* __restrict__ partials)
{
    const int se   = blockIdx.x;        // fastest: XCD = se%8 -> per-XCD weight set ~2.7MB fits L2
    const int tile = blockIdx.y;
    const int s    = se >> 3;
    const int t    = threadIdx.x;
    const int w    = t >> 6, l = t & 63;
    const int lm   = l & 15, kq = l >> 4;

    __shared__ ushort H1s[TM][D1 + 8];                  // 33792 B (aliased as H3 later)
    __shared__ ushort H2s[TM][D2 + 8];                  // 25600 B
    __shared__ __align__(16) ushort Ast[2][4][TM][8];   // 8192 B, double-buffered A stage

    // A staging identity: thread stages gathered row l, k-window [kb*32 + w*8, +8)
    const int srow = tile * TM + l;
    const int src  = srow < NPS ? srow : NPS - 1;
    const float* arowp = aev + (size_t)idx[s * NPS + src] * AEVD;
    const int wo = w * 8;

    // ================= Layer 1: [64x1008] x [1008x256], n-split (wave w: nb w*4..w*4+3) =========
    const ushort* w1se = W1p + (size_t)se * (KB1 * NB1 * 512);

    f32x4 acc1[4][4];
    #pragma unroll
    for (int mi = 0; mi < 4; ++mi)
        #pragma unroll
        for (int j = 0; j < 4; ++j) acc1[mi][j] = (f32x4){0.f, 0.f, 0.f, 0.f};

    uint4 B0[4], B1[4];
    float4 na, nbv;
    {   // stage kb=0
        int ko = wo;                      // < 1008 for all waves at kb=0
        float4 ca = *(const float4*)(arowp + ko);
        float4 cb = *(const float4*)(arowp + ko + 4);
        #pragma unroll
        for (int i = 0; i < 4; ++i)
            B0[i] = *(const uint4*)(w1se + ((size_t)(0 * NB1 + (w * 4 + i)) * 64 + l) * 8);
        short8 v;
        v[0] = (short)f2bf(ca.x); v[1] = (short)f2bf(ca.y);
        v[2] = (short)f2bf(ca.z); v[3] = (short)f2bf(ca.w);
        v[4] = (short)f2bf(cb.x); v[5] = (short)f2bf(cb.y);
        v[6] = (short)f2bf(cb.z); v[7] = (short)f2bf(cb.w);
        *(short8*)&Ast[0][w][l][0] = v;
        int k1 = 32 + wo;
        na  = *(const float4*)(arowp + k1);
        nbv = *(const float4*)(arowp + k1 + 4);
    }
    __syncthreads();

    for (int kb = 0; kb < KB1; ++kb) {
        const int nkb = kb + 1;
        if (nkb < KB1) {
            #pragma unroll
            for (int i = 0; i < 4; ++i)
                B1[i] = *(const uint4*)(w1se + ((size_t)(nkb * NB1 + (w * 4 + i)) * 64 + l) * 8);
            short8 v;
            v[0] = (short)f2bf(na.x);  v[1] = (short)f2bf(na.y);
            v[2] = (short)f2bf(na.z);  v[3] = (short)f2bf(na.w);
            v[4] = (short)f2bf(nbv.x); v[5] = (short)f2bf(nbv.y);
            v[6] = (short)f2bf(nbv.z); v[7] = (short)f2bf(nbv.w);
            *(short8*)&Ast[nkb & 1][w][l][0] = v;
            if (kb + 2 < KB1) {
                int ko = (kb + 2) * 32 + wo;
                if (ko > AEVD - 8) ko = AEVD - 8;   // clamp: pad k covered by zero weights
                na  = *(const float4*)(arowp + ko);
                nbv = *(const float4*)(arowp + ko + 4);
            }
        }
        #pragma unroll
        for (int mi = 0; mi < 4; ++mi) {
            short8 af = *(const short8*)&Ast[kb & 1][kq][mi * 16 + lm][0];
            #pragma unroll
            for (int j = 0; j < 4; ++j)
                acc1[mi][j] = __builtin_amdgcn_mfma_f32_16x16x32_bf16(af, *(short8*)&B0[j], acc1[mi][j], 0, 0, 0);
        }
        __syncthreads();
        #pragma unroll
        for (int i = 0; i < 4; ++i) B0[i] = B1[i];
    }
    // epilogue: bias + celu -> H1s row-major bf16
    #pragma unroll
    for (int j = 0; j < 4; ++j) {
        int n = (w * 4 + j) * 16 + lm;
        float bias = b1[se * D1 + n];
        #pragma unroll
        for (int mi = 0; mi < 4; ++mi)
            #pragma unroll
            for (int r = 0; r < 4; ++r)
                H1s[mi * 16 + kq * 4 + r][n] = f2bf(celu_f(acc1[mi][j][r] + bias));
    }
    __syncthreads();

    // ================= Layer 2: [64x256] x [256x192], n-split (wave w: nb w*3..w*3+2) ==========
    const ushort* w2se = W2p + (size_t)se * (KB2 * NB2 * 512);
    f32x4 acc2[4][3];
    #pragma unroll
    for (int mi = 0; mi < 4; ++mi)
        #pragma unroll
        for (int j = 0; j < 3; ++j) acc2[mi][j] = (f32x4){0.f, 0.f, 0.f, 0.f};

    uint4 C0[3], C1[3];
    #pragma unroll
    for (int i = 0; i < 3; ++i)
        C0[i] = *(const uint4*)(w2se + ((size_t)(0 * NB2 + (w * 3 + i)) * 64 + l) * 8);

    for (int kb = 0; kb < KB2; ++kb) {     // no barriers: H1s is stable
        if (kb + 1 < KB2) {
            #pragma unroll
            for (int i = 0; i < 3; ++i)
                C1[i] = *(const uint4*)(w2se + ((size_t)((kb + 1) * NB2 + (w * 3 + i)) * 64 + l) * 8);
        }
        #pragma unroll
        for (int mi = 0; mi < 4; ++mi) {
            short8 af = *(const short8*)&H1s[mi * 16 + lm][kb * 32 + kq * 8];
            #pragma unroll
            for (int j = 0; j < 3; ++j)
                acc2[mi][j] = __builtin_amdgcn_mfma_f32_16x16x32_bf16(af, *(short8*)&C0[j], acc2[mi][j], 0, 0, 0);
        }
        #pragma unroll
        for (int i = 0; i < 3; ++i) C0[i] = C1[i];
    }
    #pragma unroll
    for (int j = 0; j < 3; ++j) {
        int n = (w * 3 + j) * 16 + lm;
        float bias = b2[se * D2 + n];
        #pragma unroll
        for (int mi = 0; mi < 4; ++mi)
            #pragma unroll
            for (int r = 0; r < 4; ++r)
                H2s[mi * 16 + kq * 4 + r][n] = f2bf(celu_f(acc2[mi][j][r] + bias));
    }
    __syncthreads();   // H2 ready; H1 now dead (all waves past their L2 reads)

    // ================= Layer 3: [64x192] x [192x160], n-split (waves get 3/3/2/2 nb) ===========
    const ushort* w3se = W3p + (size_t)se * (KB3 * NB3 * 512);
    const int cw = (w < 2) ? 3 : 2;
    const int ow = (w < 2) ? w * 3 : 6 + (w - 2) * 2;
    f32x4 acc3[4][3];
    #pragma unroll
    for (int mi = 0; mi < 4; ++mi)
        #pragma unroll
        for (int j = 0; j < 3; ++j) acc3[mi][j] = (f32x4){0.f, 0.f, 0.f, 0.f};

    uint4 D0[3], D1v[3];
    #pragma unroll
    for (int i = 0; i < 3; ++i)
        if (i < cw)
            D0[i] = *(const uint4*)(w3se + ((size_t)(0 * NB3 + (ow + i)) * 64 + l) * 8);

    for (int kb = 0; kb < KB3; ++kb) {     // no barriers: H2s is stable
        if (kb + 1 < KB3) {
            #pragma unroll
            for (int i = 0; i < 3; ++i)
                if (i < cw)
                    D1v[i] = *(const uint4*)(w3se + ((size_t)((kb + 1) * NB3 + (ow + i)) * 64 + l) * 8);
        }
        #pragma unroll
        for (int mi = 0; mi < 4; ++mi) {
            short8 af = *(const short8*)&H2s[mi * 16 + lm][kb * 32 + kq * 8];
            #pragma unroll
            for (int j = 0; j < 3; ++j)
                if (j < cw)
                    acc3[mi][j] = __builtin_amdgcn_mfma_f32_16x16x32_bf16(af, *(short8*)&D0[j], acc3[mi][j], 0, 0, 0);
        }
        #pragma unroll
        for (int i = 0; i < 3; ++i) D0[i] = D1v[i];
    }
    ushort* H3 = &H1s[0][0];               // alias: [64][168] bf16
    #pragma unroll
    for (int j = 0; j < 3; ++j) {
        if (j < cw) {
            int n = (ow + j) * 16 + lm;
            float bias = b3[se * D3 + n];
            #pragma unroll
            for (int mi = 0; mi < 4; ++mi)
                #pragma unroll
                for (int r = 0; r < 4; ++r)
                    H3[(mi * 16 + kq * 4 + r) * (D3 + 8) + n] = f2bf(celu_f(acc3[mi][j][r] + bias));
        }
    }
    // stage W4 (fp32) into dead Ast region
    float* Wf = (float*)&Ast[0][0][0][0];
    if (t < D3) Wf[t] = W4[se * D3 + t];
    __syncthreads();

    // ================= Layer 4 + block reduction =================
    const int row = t >> 2, seg = t & 3;
    float sum = 0.0f;
    #pragma unroll
    for (int jj = 0; jj < 40; ++jj) {
        int k = seg * 40 + jj;
        sum += bf2f(H3[row * (D3 + 8) + k]) * Wf[k];
    }
    sum += __shfl_xor(sum, 1);
    sum += __shfl_xor(sum, 2);
    float rowval = (tile * TM + row < NPS) ? (sum + b4[se]) : 0.0f;
    float* Rs = Wf + 256;
    if (seg == 0) Rs[row] = rowval;
    __syncthreads();
    if (t == 0) {
        float tot = 0.0f;
        #pragma unroll
        for (int r = 0; r < TM; ++r) tot += Rs[r];
        partials[tile * (S_ * E_) + se] = tot;
    }
}

__global__ void reduce_partials(const float* __restrict__ p, int n, float* __restrict__ out)
{
    float s = 0.0f;
    for (int i = threadIdx.x; i < n; i += 256) s += p[i];
    #pragma unroll
    for (int o = 32; o > 0; o >>= 1) s += __shfl_xor(s, o);
    __shared__ float sm[4];
    if ((threadIdx.x & 63) == 0) sm[threadIdx.x >> 6] = s;
    __syncthreads();
    if (threadIdx.x == 0) out[0] = (sm[0] + sm[1] + sm[2] + sm[3]) * (1.0f / E_);
}

extern "C" void kernel_launch(void* const* d_in, const int* in_sizes, int n_in,
                              void* d_out, int out_size, void* d_ws, size_t ws_size,
                              hipStream_t stream)
{
    const float* aev = (const float*)d_in[0];
    const int*   idx = (const int*)  d_in[2];
    const float* W1  = (const float*)d_in[3];
    const float* b1  = (const float*)d_in[4];
    const float* W2  = (const float*)d_in[5];
    const float* b2  = (const float*)d_in[6];
    const float* W3  = (const float*)d_in[7];
    const float* b3  = (const float*)d_in[8];
    const float* W4  = (const float*)d_in[9];
    const float* b4  = (const float*)d_in[10];
    float* out = (float*)d_out;

    ushort* w1p = (ushort*)d_ws;
    ushort* w2p = w1p + (size_t)S_ * E_ * KB1 * NB1 * 512;
    ushort* w3p = w2p + (size_t)S_ * E_ * KB2 * NB2 * 512;
    float* partials = (float*)(w3p + (size_t)S_ * E_ * KB3 * NB3 * 512);

    pack_w<<<S_ * E_ * KB1, 256, 0, stream>>>(W1, w1p, AEVD, KB1, NB1, D1);
    pack_w<<<S_ * E_ * KB2, 256, 0, stream>>>(W2, w2p, D1,   KB2, NB2, D2);
    pack_w<<<S_ * E_ * KB3, 256, 0, stream>>>(W3, w3p, D2,   KB3, NB3, D3);

    dim3 grid(S_ * E_, NT);
    ani_mfma<<<grid, 256, 0, stream>>>(aev, idx, w1p, w2p, w3p,
                                       b1, b2, b3, W4, b4, partials);
    reduce_partials<<<1, 256, 0, stream>>>(partials, NT * S_ * E_, out);
}

// Round 4
// 807.655 us; speedup vs baseline: 7.2507x; 1.0364x over previous
//
#include <hip/hip_runtime.h>

#define S_    4
#define E_    8
#define NPS   12500
#define AEVD  1008
#define D1    256
#define D2    192
#define D3    160
#define TM    64
#define NT    ((NPS + TM - 1) / TM)    // 196
#define ALPHA 0.1f

// packed-weight geometry: [kb][nb][lane(64)][8] bf16, K padded to kb*32
#define KB1 32
#define NB1 16
#define KB2 8
#define NB2 12
#define KB3 6
#define NB3 10

typedef __attribute__((ext_vector_type(8))) short short8;
typedef __attribute__((ext_vector_type(4))) float f32x4;

__device__ __forceinline__ ushort f2bf(float f) {
    unsigned u = __float_as_uint(f);
    unsigned r = u + 0x7FFFu + ((u >> 16) & 1u);   // RNE
    return (ushort)(r >> 16);
}
__device__ __forceinline__ float bf2f(ushort u) {
    return __uint_as_float(((unsigned)u) << 16);
}
__device__ __forceinline__ float celu_f(float v) {
    return v > 0.0f ? v : ALPHA * (__expf(v * (1.0f / ALPHA)) - 1.0f);
}
// CK-style barrier: drains LDS ops only; global register-loads stay in flight.
__device__ __forceinline__ void sync_lds() {
    asm volatile("s_waitcnt lgkmcnt(0)" ::: "memory");
    __builtin_amdgcn_s_barrier();
}

// ---------------- weight pre-pack: fp32 [se][K][N] -> bf16 B-fragment order ----------------
__device__ __forceinline__ void pack_body(const float* __restrict__ W, ushort* __restrict__ out,
                                          int Ksrc, int kbs, int nbs, int Nsrc, int b)
{
    const int kb = b % kbs;
    const int se = b / kbs;
    const int t  = threadIdx.x;
    const int l  = t & 63, q = t >> 6;
    const float* Wse = W + (size_t)se * Ksrc * Nsrc;
    for (int i = 0; i < 4; ++i) {
        int nb = q + i * 4;
        if (nb >= nbs) break;
        int n = nb * 16 + (l & 15);
        ushort v[8];
        #pragma unroll
        for (int j = 0; j < 8; ++j) {
            int k = kb * 32 + ((l >> 4) << 3) + j;
            float x = (k < Ksrc) ? Wse[(size_t)k * Nsrc + n] : 0.0f;
            v[j] = f2bf(x);
        }
        uint4 u;
        u.x = (unsigned)v[0] | ((unsigned)v[1] << 16);
        u.y = (unsigned)v[2] | ((unsigned)v[3] << 16);
        u.z = (unsigned)v[4] | ((unsigned)v[5] << 16);
        u.w = (unsigned)v[6] | ((unsigned)v[7] << 16);
        *(uint4*)(out + ((((size_t)se * kbs + kb) * nbs + nb) * 64 + l) * 8) = u;
    }
}

__global__ void pack_all(const float* __restrict__ W1, const float* __restrict__ W2,
                         const float* __restrict__ W3,
                         ushort* __restrict__ o1, ushort* __restrict__ o2, ushort* __restrict__ o3)
{
    int b = blockIdx.x;
    if (b < S_ * E_ * KB1)                    pack_body(W1, o1, AEVD, KB1, NB1, D1, b);
    else if (b < S_ * E_ * (KB1 + KB2))       pack_body(W2, o2, D1,   KB2, NB2, D2, b - S_ * E_ * KB1);
    else                                      pack_body(W3, o3, D2,   KB3, NB3, D3, b - S_ * E_ * (KB1 + KB2));
}

// ---------------- fused 4-layer MFMA kernel ----------------
// grid(tile, se): tile fastest -> each XCD sees ~1-2 se weight sets (L2-resident).
// block: 64 atoms x one (s,e); wave w owns an n-slice; B in registers, parity double-buffered.
__global__ __launch_bounds__(256, 2)
void ani_mfma(const float* __restrict__ aev, const int* __restrict__ idx,
              const ushort* __restrict__ W1p, const ushort* __restrict__ W2p,
              const ushort* __restrict__ W3p,
              const float* __restrict__ b1, const float* __restrict__ b2,
              const float* __restrict__ b3,
              const float* __restrict__ W4, const float* __restrict__ b4,
              float* __restrict__ partials)
{
    const int tile = blockIdx.x;
    const int se   = blockIdx.y;
    const int s    = se >> 3;
    const int t    = threadIdx.x;
    const int w    = t >> 6, l = t & 63;
    const int lm   = l & 15, kq = l >> 4;

    __shared__ ushort H1s[TM][D1 + 8];                  // 33792 B (aliased as H3 later)
    __shared__ ushort H2s[TM][D2 + 8];                  // 25600 B
    __shared__ __align__(16) ushort Ast[2][4][TM][8];   // 8192 B, double-buffered A stage

    // A staging identity: thread stages gathered row l, k-window [kb*32 + w*8, +8)
    const int srow = tile * TM + l;
    const int src  = srow < NPS ? srow : NPS - 1;
    const float* arowp = aev + (size_t)idx[s * NPS + src] * AEVD;
    const int wo = w * 8;

    // ================= Layer 1: [64x1008] x [1008x256], wave w: nb w*4..w*4+3 =========
    const ushort* w1se = W1p + (size_t)se * (KB1 * NB1 * 512);

    f32x4 acc1[4][4];
    #pragma unroll
    for (int mi = 0; mi < 4; ++mi)
        #pragma unroll
        for (int j = 0; j < 4; ++j) acc1[mi][j] = (f32x4){0.f, 0.f, 0.f, 0.f};

    uint4 B0[4], B1[4];
    float4 na, nbv;

    auto loadB = [&](uint4* Bt, int kb) {
        #pragma unroll
        for (int i = 0; i < 4; ++i)
            Bt[i] = *(const uint4*)(w1se + ((size_t)(kb * NB1 + (w * 4 + i)) * 64 + l) * 8);
    };
    // write Ast[kbw&1] with data in na/nbv (kbw's window), then prefetch kbw+1's window
    auto stageA = [&](int kbw) {
        short8 v;
        v[0] = (short)f2bf(na.x);  v[1] = (short)f2bf(na.y);
        v[2] = (short)f2bf(na.z);  v[3] = (short)f2bf(na.w);
        v[4] = (short)f2bf(nbv.x); v[5] = (short)f2bf(nbv.y);
        v[6] = (short)f2bf(nbv.z); v[7] = (short)f2bf(nbv.w);
        *(short8*)&Ast[kbw & 1][w][l][0] = v;
        if (kbw + 1 < KB1) {
            int ko = (kbw + 1) * 32 + wo;
            if (ko > AEVD - 8) ko = AEVD - 8;   // clamp: pad k covered by zero weights
            na  = *(const float4*)(arowp + ko);
            nbv = *(const float4*)(arowp + ko + 4);
        }
    };
    auto mfma16 = [&](int buf, uint4* Bt) {
        #pragma unroll
        for (int mi = 0; mi < 4; ++mi) {
            short8 af = *(const short8*)&Ast[buf][kq][mi * 16 + lm][0];
            #pragma unroll
            for (int j = 0; j < 4; ++j)
                acc1[mi][j] = __builtin_amdgcn_mfma_f32_16x16x32_bf16(af, *(short8*)&Bt[j], acc1[mi][j], 0, 0, 0);
        }
    };

    {   // prologue: stage kb=0, prefetch aev kb=1, B kb=0 and kb=1
        float4 ca = *(const float4*)(arowp + wo);
        float4 cb = *(const float4*)(arowp + wo + 4);
        short8 v;
        v[0] = (short)f2bf(ca.x); v[1] = (short)f2bf(ca.y);
        v[2] = (short)f2bf(ca.z); v[3] = (short)f2bf(ca.w);
        v[4] = (short)f2bf(cb.x); v[5] = (short)f2bf(cb.y);
        v[6] = (short)f2bf(cb.z); v[7] = (short)f2bf(cb.w);
        *(short8*)&Ast[0][w][l][0] = v;
        na  = *(const float4*)(arowp + 32 + wo);
        nbv = *(const float4*)(arowp + 32 + wo + 4);
        loadB(B0, 0);
        loadB(B1, 1);
        sync_lds();
    }

    for (int kb = 0; kb < KB1; kb += 2) {
        // sub-step kb (even): reads Ast[0]+B0; stages Ast[1] for kb+1
        if (kb + 1 < KB1) stageA(kb + 1);
        mfma16(0, B0);
        if (kb + 2 < KB1) loadB(B0, kb + 2);
        sync_lds();
        // sub-step kb+1 (odd): reads Ast[1]+B1; stages Ast[0] for kb+2
        if (kb + 2 < KB1) stageA(kb + 2);
        mfma16(1, B1);
        if (kb + 3 < KB1) loadB(B1, kb + 3);
        sync_lds();
    }
    // epilogue: bias + celu -> H1s row-major bf16
    #pragma unroll
    for (int j = 0; j < 4; ++j) {
        int n = (w * 4 + j) * 16 + lm;
        float bias = b1[se * D1 + n];
        #pragma unroll
        for (int mi = 0; mi < 4; ++mi)
            #pragma unroll
            for (int r = 0; r < 4; ++r)
                H1s[mi * 16 + kq * 4 + r][n] = f2bf(celu_f(acc1[mi][j][r] + bias));
    }
    sync_lds();

    // ================= Layer 2: [64x256] x [256x192], wave w: nb w*3..w*3+2 ==========
    const ushort* w2se = W2p + (size_t)se * (KB2 * NB2 * 512);
    f32x4 acc2[4][3];
    #pragma unroll
    for (int mi = 0; mi < 4; ++mi)
        #pragma unroll
        for (int j = 0; j < 3; ++j) acc2[mi][j] = (f32x4){0.f, 0.f, 0.f, 0.f};

    uint4 C0[3], C1[3];
    auto loadC = [&](uint4* Ct, int kb) {
        #pragma unroll
        for (int i = 0; i < 3; ++i)
            Ct[i] = *(const uint4*)(w2se + ((size_t)(kb * NB2 + (w * 3 + i)) * 64 + l) * 8);
    };
    auto mfma12 = [&](int kb, uint4* Ct) {
        #pragma unroll
        for (int mi = 0; mi < 4; ++mi) {
            short8 af = *(const short8*)&H1s[mi * 16 + lm][kb * 32 + kq * 8];
            #pragma unroll
            for (int j = 0; j < 3; ++j)
                acc2[mi][j] = __builtin_amdgcn_mfma_f32_16x16x32_bf16(af, *(short8*)&Ct[j], acc2[mi][j], 0, 0, 0);
        }
    };
    loadC(C0, 0);
    loadC(C1, 1);
    #pragma unroll
    for (int kb = 0; kb < KB2; kb += 2) {       // no barriers: H1s stable
        mfma12(kb, C0);
        if (kb + 2 < KB2) loadC(C0, kb + 2);
        mfma12(kb + 1, C1);
        if (kb + 3 < KB2) loadC(C1, kb + 3);
    }
    #pragma unroll
    for (int j = 0; j < 3; ++j) {
        int n = (w * 3 + j) * 16 + lm;
        float bias = b2[se * D2 + n];
        #pragma unroll
        for (int mi = 0; mi < 4; ++mi)
            #pragma unroll
            for (int r = 0; r < 4; ++r)
                H2s[mi * 16 + kq * 4 + r][n] = f2bf(celu_f(acc2[mi][j][r] + bias));
    }
    sync_lds();   // H2 ready; H1 reads all done -> H3 alias safe after this

    // ================= Layer 3: [64x192] x [192x160], waves get 3/3/2/2 nb ===========
    const ushort* w3se = W3p + (size_t)se * (KB3 * NB3 * 512);
    const int cw = (w < 2) ? 3 : 2;
    const int ow = (w < 2) ? w * 3 : 6 + (w - 2) * 2;
    f32x4 acc3[4][3];
    #pragma unroll
    for (int mi = 0; mi < 4; ++mi)
        #pragma unroll
        for (int j = 0; j < 3; ++j) acc3[mi][j] = (f32x4){0.f, 0.f, 0.f, 0.f};

    uint4 D0[3], D1v[3];
    auto loadD = [&](uint4* Dt, int kb) {
        #pragma unroll
        for (int i = 0; i < 3; ++i)
            if (i < cw)
                Dt[i] = *(const uint4*)(w3se + ((size_t)(kb * NB3 + (ow + i)) * 64 + l) * 8);
    };
    auto mfma10 = [&](int kb, uint4* Dt) {
        #pragma unroll
        for (int mi = 0; mi < 4; ++mi) {
            short8 af = *(const short8*)&H2s[mi * 16 + lm][kb * 32 + kq * 8];
            #pragma unroll
            for (int j = 0; j < 3; ++j)
                if (j < cw)
                    acc3[mi][j] = __builtin_amdgcn_mfma_f32_16x16x32_bf16(af, *(short8*)&Dt[j], acc3[mi][j], 0, 0, 0);
        }
    };
    loadD(D0, 0);
    loadD(D1v, 1);
    #pragma unroll
    for (int kb = 0; kb < KB3; kb += 2) {       // no barriers: H2s stable
        mfma10(kb, D0);
        if (kb + 2 < KB3) loadD(D0, kb + 2);
        mfma10(kb + 1, D1v);
        if (kb + 3 < KB3) loadD(D1v, kb + 3);
    }
    ushort* H3 = &H1s[0][0];               // alias: [64][168] bf16
    #pragma unroll
    for (int j = 0; j < 3; ++j) {
        if (j < cw) {
            int n = (ow + j) * 16 + lm;
            float bias = b3[se * D3 + n];
            #pragma unroll
            for (int mi = 0; mi < 4; ++mi)
                #pragma unroll
                for (int r = 0; r < 4; ++r)
                    H3[(mi * 16 + kq * 4 + r) * (D3 + 8) + n] = f2bf(celu_f(acc3[mi][j][r] + bias));
        }
    }
    // stage W4 (fp32) into dead Ast region
    float* Wf = (float*)&Ast[0][0][0][0];
    if (t < D3) Wf[t] = W4[se * D3 + t];
    sync_lds();

    // ================= Layer 4 + block reduction =================
    const int row = t >> 2, seg = t & 3;
    float sum = 0.0f;
    #pragma unroll
    for (int jj = 0; jj < 40; ++jj) {
        int k = seg * 40 + jj;
        sum += bf2f(H3[row * (D3 + 8) + k]) * Wf[k];
    }
    sum += __shfl_xor(sum, 1);
    sum += __shfl_xor(sum, 2);
    float rowval = (tile * TM + row < NPS) ? (sum + b4[se]) : 0.0f;
    float* Rs = Wf + 256;
    if (seg == 0) Rs[row] = rowval;
    __syncthreads();
    if (t == 0) {
        float tot = 0.0f;
        #pragma unroll
        for (int r = 0; r < TM; ++r) tot += Rs[r];
        partials[tile * (S_ * E_) + se] = tot;
    }
}

__global__ void reduce_partials(const float* __restrict__ p, int n, float* __restrict__ out)
{
    float s = 0.0f;
    for (int i = threadIdx.x; i < n; i += 256) s += p[i];
    #pragma unroll
    for (int o = 32; o > 0; o >>= 1) s += __shfl_xor(s, o);
    __shared__ float sm[4];
    if ((threadIdx.x & 63) == 0) sm[threadIdx.x >> 6] = s;
    __syncthreads();
    if (threadIdx.x == 0) out[0] = (sm[0] + sm[1] + sm[2] + sm[3]) * (1.0f / E_);
}

extern "C" void kernel_launch(void* const* d_in, const int* in_sizes, int n_in,
                              void* d_out, int out_size, void* d_ws, size_t ws_size,
                              hipStream_t stream)
{
    const float* aev = (const float*)d_in[0];
    const int*   idx = (const int*)  d_in[2];
    const float* W1  = (const float*)d_in[3];
    const float* b1  = (const float*)d_in[4];
    const float* W2  = (const float*)d_in[5];
    const float* b2  = (const float*)d_in[6];
    const float* W3  = (const float*)d_in[7];
    const float* b3  = (const float*)d_in[8];
    const float* W4  = (const float*)d_in[9];
    const float* b4  = (const float*)d_in[10];
    float* out = (float*)d_out;

    ushort* w1p = (ushort*)d_ws;
    ushort* w2p = w1p + (size_t)S_ * E_ * KB1 * NB1 * 512;
    ushort* w3p = w2p + (size_t)S_ * E_ * KB2 * NB2 * 512;
    float* partials = (float*)(w3p + (size_t)S_ * E_ * KB3 * NB3 * 512);

    pack_all<<<S_ * E_ * (KB1 + KB2 + KB3), 256, 0, stream>>>(W1, W2, W3, w1p, w2p, w3p);

    dim3 grid(NT, S_ * E_);   // tile fastest: per-XCD weight working set stays L2-resident
    ani_mfma<<<grid, 256, 0, stream>>>(aev, idx, w1p, w2p, w3p,
                                       b1, b2, b3, W4, b4, partials);
    reduce_partials<<<1, 256, 0, stream>>>(partials, NT * S_ * E_, out);
}

// Round 5
// 790.127 us; speedup vs baseline: 7.4116x; 1.0222x over previous
//
#include <hip/hip_runtime.h>

#define S_    4
#define E_    8
#define NPS   12500
#define AEVD  1008
#define D1    256
#define D2    192
#define D3    160
#define TM    64
#define NT    ((NPS + TM - 1) / TM)    // 196
#define TG    8                        // tiles per supergroup
#define NG    ((NT + TG - 1) / TG)     // 25
#define ALPHA 0.1f

// packed-weight geometry: [kb][nb][lane(64)][8] bf16, K padded to kb*32.
// NOTE: B-frag layout of W == A-frag layout of W^T — same bytes serve both.
#define KB1 32
#define NB1 16
#define KB2 8
#define NB2 12
#define KB3 6
#define NB3 10

typedef __attribute__((ext_vector_type(8))) short short8;
typedef __attribute__((ext_vector_type(4))) float f32x4;

__device__ __forceinline__ ushort f2bf(float f) {
    unsigned u = __float_as_uint(f);
    unsigned r = u + 0x7FFFu + ((u >> 16) & 1u);   // RNE
    return (ushort)(r >> 16);
}
__device__ __forceinline__ float celu_f(float v) {
    return v > 0.0f ? v : ALPHA * (__expf(v * (1.0f / ALPHA)) - 1.0f);
}
// LDS-only barrier: global register-loads stay in flight.
__device__ __forceinline__ void sync_lds() {
    asm volatile("s_waitcnt lgkmcnt(0)" ::: "memory");
    __builtin_amdgcn_s_barrier();
}

// ---------------- weight pre-pack: fp32 [se][K][N] -> bf16 fragment order ----------------
__device__ __forceinline__ void pack_body(const float* __restrict__ W, ushort* __restrict__ out,
                                          int Ksrc, int kbs, int nbs, int Nsrc, int b)
{
    const int kb = b % kbs;
    const int se = b / kbs;
    const int t  = threadIdx.x;
    const int l  = t & 63, q = t >> 6;
    const float* Wse = W + (size_t)se * Ksrc * Nsrc;
    for (int i = 0; i < 4; ++i) {
        int nb = q + i * 4;
        if (nb >= nbs) break;
        int n = nb * 16 + (l & 15);
        ushort v[8];
        #pragma unroll
        for (int j = 0; j < 8; ++j) {
            int k = kb * 32 + ((l >> 4) << 3) + j;
            float x = (k < Ksrc) ? Wse[(size_t)k * Nsrc + n] : 0.0f;
            v[j] = f2bf(x);
        }
        uint4 u;
        u.x = (unsigned)v[0] | ((unsigned)v[1] << 16);
        u.y = (unsigned)v[2] | ((unsigned)v[3] << 16);
        u.z = (unsigned)v[4] | ((unsigned)v[5] << 16);
        u.w = (unsigned)v[6] | ((unsigned)v[7] << 16);
        *(uint4*)(out + ((((size_t)se * kbs + kb) * nbs + nb) * 64 + l) * 8) = u;
    }
}

__global__ void pack_all(const float* __restrict__ W1, const float* __restrict__ W2,
                         const float* __restrict__ W3,
                         ushort* __restrict__ o1, ushort* __restrict__ o2, ushort* __restrict__ o3)
{
    int b = blockIdx.x;
    if (b < S_ * E_ * KB1)                    pack_body(W1, o1, AEVD, KB1, NB1, D1, b);
    else if (b < S_ * E_ * (KB1 + KB2))       pack_body(W2, o2, D1,   KB2, NB2, D2, b - S_ * E_ * KB1);
    else                                      pack_body(W3, o3, D2,   KB3, NB3, D3, b - S_ * E_ * (KB1 + KB2));
}

// ---------------- fused 4-layer MFMA kernel ----------------
// L1: n-split cooperative (Ast staging, barrier/kb). L2-L4: m-split transposed
// (H as B-operand, W as A-operand), fully wave-local, barrier-free.
__global__ __launch_bounds__(256, 3)
void ani_mfma(const float* __restrict__ aev, const int* __restrict__ idx,
              const ushort* __restrict__ W1p, const ushort* __restrict__ W2p,
              const ushort* __restrict__ W3p,
              const float* __restrict__ b1, const float* __restrict__ b2,
              const float* __restrict__ b3,
              const float* __restrict__ W4, const float* __restrict__ b4,
              float* __restrict__ partials)
{
    const int se   = blockIdx.x & 31;      // XCD = blkid%8 = se%8 -> 4 weight sets/XCD (~2.7MB, L2-resident)
    const int ti   = blockIdx.x >> 5;
    const int tile = blockIdx.y * TG + ti; // 8 tiles x 32 se per group -> aev reused 32x while L2/L3-hot
    if (tile >= NT) return;
    const int s = se >> 3;
    const int t = threadIdx.x;
    const int w = t >> 6, l = t & 63;
    const int lm = l & 15, kq = l >> 4;

    __shared__ ushort H1s[TM][D1 + 8];                  // 33792 B; rows reused as per-wave H2 later
    __shared__ __align__(16) ushort Ast[2][4][TM][8];   // 8192 B; aliased as float red[] at the end

    const int srow = tile * TM + l;
    const int src  = srow < NPS ? srow : NPS - 1;
    const float* arowp = aev + (size_t)idx[s * NPS + src] * AEVD;
    const int wo = w * 8;

    // ================= Layer 1: n-split, cooperative A-staging =================
    const ushort* w1se = W1p + (size_t)se * (KB1 * NB1 * 512);

    f32x4 acc1[4][4];
    #pragma unroll
    for (int mi = 0; mi < 4; ++mi)
        #pragma unroll
        for (int j = 0; j < 4; ++j) acc1[mi][j] = (f32x4){0.f, 0.f, 0.f, 0.f};

    uint4 B0[4], B1[4];
    float4 na, nbv;

    auto loadB = [&](uint4* Bt, int kb) {
        #pragma unroll
        for (int i = 0; i < 4; ++i)
            Bt[i] = *(const uint4*)(w1se + ((size_t)(kb * NB1 + (w * 4 + i)) * 64 + l) * 8);
    };
    auto stageA = [&](int kbw) {
        short8 v;
        v[0] = (short)f2bf(na.x);  v[1] = (short)f2bf(na.y);
        v[2] = (short)f2bf(na.z);  v[3] = (short)f2bf(na.w);
        v[4] = (short)f2bf(nbv.x); v[5] = (short)f2bf(nbv.y);
        v[6] = (short)f2bf(nbv.z); v[7] = (short)f2bf(nbv.w);
        *(short8*)&Ast[kbw & 1][w][l][0] = v;
        if (kbw + 1 < KB1) {
            int ko = (kbw + 1) * 32 + wo;
            if (ko > AEVD - 8) ko = AEVD - 8;   // pad k covered by zero weights
            na  = *(const float4*)(arowp + ko);
            nbv = *(const float4*)(arowp + ko + 4);
        }
    };
    auto mfma16 = [&](int buf, uint4* Bt) {
        #pragma unroll
        for (int mi = 0; mi < 4; ++mi) {
            short8 af = *(const short8*)&Ast[buf][kq][mi * 16 + lm][0];
            #pragma unroll
            for (int j = 0; j < 4; ++j)
                acc1[mi][j] = __builtin_amdgcn_mfma_f32_16x16x32_bf16(af, *(short8*)&Bt[j], acc1[mi][j], 0, 0, 0);
        }
    };

    {   // prologue
        float4 ca = *(const float4*)(arowp + wo);
        float4 cb = *(const float4*)(arowp + wo + 4);
        short8 v;
        v[0] = (short)f2bf(ca.x); v[1] = (short)f2bf(ca.y);
        v[2] = (short)f2bf(ca.z); v[3] = (short)f2bf(ca.w);
        v[4] = (short)f2bf(cb.x); v[5] = (short)f2bf(cb.y);
        v[6] = (short)f2bf(cb.z); v[7] = (short)f2bf(cb.w);
        *(short8*)&Ast[0][w][l][0] = v;
        na  = *(const float4*)(arowp + 32 + wo);
        nbv = *(const float4*)(arowp + 32 + wo + 4);
        loadB(B0, 0);
        loadB(B1, 1);
        sync_lds();
    }

    for (int kb = 0; kb < KB1; kb += 2) {
        if (kb + 1 < KB1) stageA(kb + 1);
        mfma16(0, B0);
        if (kb + 2 < KB1) loadB(B0, kb + 2);
        sync_lds();
        if (kb + 2 < KB1) stageA(kb + 2);
        mfma16(1, B1);
        if (kb + 3 < KB1) loadB(B1, kb + 3);
        sync_lds();
    }
    // L1 epilogue: bias+celu -> H1 (atom-major bf16)
    #pragma unroll
    for (int j = 0; j < 4; ++j) {
        int n = (w * 4 + j) * 16 + lm;
        float bias = b1[se * D1 + n];
        #pragma unroll
        for (int mi = 0; mi < 4; ++mi)
            #pragma unroll
            for (int r = 0; r < 4; ++r)
                H1s[mi * 16 + kq * 4 + r][n] = f2bf(celu_f(acc1[mi][j][r] + bias));
    }
    sync_lds();   // LAST barrier in the kernel: H1 visible to all waves

    // ================= Layers 2-4: m-split transposed, wave-local =================
    // wave w owns atoms w*16..w*16+15; lane owns row (atom) w*16+lm.
    ushort* hrow = &H1s[w * 16 + lm][0];

    // ---- Layer 2: H2^T = W2^T (A-op, regs) x H1^T (B-op = own-row b128 reads) ----
    const ushort* w2se = W2p + (size_t)se * (KB2 * NB2 * 512);
    f32x4 acc2[NB2];
    #pragma unroll
    for (int i = 0; i < NB2; ++i) acc2[i] = (f32x4){0.f, 0.f, 0.f, 0.f};

    #pragma unroll
    for (int ch = 0; ch < 2; ++ch) {
        const int mb0 = ch * 6;
        uint4 A0[6], A1[6];
        auto AL2 = [&](int kb, int i) {
            return *(const uint4*)(w2se + ((size_t)(kb * NB2 + (mb0 + i)) * 64 + l) * 8);
        };
        #pragma unroll
        for (int i = 0; i < 6; ++i) A0[i] = AL2(0, i);
        short8 bf0 = *(const short8*)(hrow + 0 * 32 + kq * 8);
        #pragma unroll
        for (int kb = 0; kb < KB2; kb += 2) {
            short8 bf1 = *(const short8*)(hrow + (kb + 1) * 32 + kq * 8);
            #pragma unroll
            for (int i = 0; i < 6; ++i) A1[i] = AL2(kb + 1, i);
            #pragma unroll
            for (int i = 0; i < 6; ++i)
                acc2[mb0 + i] = __builtin_amdgcn_mfma_f32_16x16x32_bf16(*(short8*)&A0[i], bf0, acc2[mb0 + i], 0, 0, 0);
            if (kb + 2 < KB2) {
                bf0 = *(const short8*)(hrow + (kb + 2) * 32 + kq * 8);
                #pragma unroll
                for (int i = 0; i < 6; ++i) A0[i] = AL2(kb + 2, i);
            }
            #pragma unroll
            for (int i = 0; i < 6; ++i)
                acc2[mb0 + i] = __builtin_amdgcn_mfma_f32_16x16x32_bf16(*(short8*)&A1[i], bf1, acc2[mb0 + i], 0, 0, 0);
        }
    }
    // L2 epilogue: lane writes 4 consecutive features of ITS OWN row (b64), overwriting H1->H2.
    // Safe: only this lane ever read this row (per-lane row ownership).
    #pragma unroll
    for (int mb = 0; mb < NB2; ++mb) {
        float4 bv = *(const float4*)&b2[se * D2 + mb * 16 + kq * 4];
        uint2 u;
        u.x = (unsigned)f2bf(celu_f(acc2[mb][0] + bv.x)) | ((unsigned)f2bf(celu_f(acc2[mb][1] + bv.y)) << 16);
        u.y = (unsigned)f2bf(celu_f(acc2[mb][2] + bv.z)) | ((unsigned)f2bf(celu_f(acc2[mb][3] + bv.w)) << 16);
        *(uint2*)(hrow + mb * 16 + kq * 4) = u;
    }

    // ---- Layer 3: H3^T = W3^T x H2^T (same structure, K=192) ----
    const ushort* w3se = W3p + (size_t)se * (KB3 * NB3 * 512);
    f32x4 acc3[NB3];
    #pragma unroll
    for (int i = 0; i < NB3; ++i) acc3[i] = (f32x4){0.f, 0.f, 0.f, 0.f};

    #pragma unroll
    for (int ch = 0; ch < 2; ++ch) {
        const int mb0 = ch * 5;
        uint4 A0[5], A1[5];
        auto AL3 = [&](int kb, int i) {
            return *(const uint4*)(w3se + ((size_t)(kb * NB3 + (mb0 + i)) * 64 + l) * 8);
        };
        #pragma unroll
        for (int i = 0; i < 5; ++i) A0[i] = AL3(0, i);
        short8 bf0 = *(const short8*)(hrow + 0 * 32 + kq * 8);
        #pragma unroll
        for (int kb = 0; kb < KB3; kb += 2) {
            short8 bf1 = *(const short8*)(hrow + (kb + 1) * 32 + kq * 8);
            #pragma unroll
            for (int i = 0; i < 5; ++i) A1[i] = AL3(kb + 1, i);
            #pragma unroll
            for (int i = 0; i < 5; ++i)
                acc3[mb0 + i] = __builtin_amdgcn_mfma_f32_16x16x32_bf16(*(short8*)&A0[i], bf0, acc3[mb0 + i], 0, 0, 0);
            if (kb + 2 < KB3) {
                bf0 = *(const short8*)(hrow + (kb + 2) * 32 + kq * 8);
                #pragma unroll
                for (int i = 0; i < 5; ++i) A0[i] = AL3(kb + 2, i);
            }
            #pragma unroll
            for (int i = 0; i < 5; ++i)
                acc3[mb0 + i] = __builtin_amdgcn_mfma_f32_16x16x32_bf16(*(short8*)&A1[i], bf1, acc3[mb0 + i], 0, 0, 0);
        }
    }

    // ---- Layer 4: fold entirely in registers. lane's acc3[mb][r] = H3pre(atom=w*16+lm, n3=mb*16+kq*4+r) ----
    float e = 0.0f;
    #pragma unroll
    for (int mb = 0; mb < NB3; ++mb) {
        float4 b3v = *(const float4*)&b3[se * D3 + mb * 16 + kq * 4];
        float4 w4v = *(const float4*)&W4[se * D3 + mb * 16 + kq * 4];
        e += celu_f(acc3[mb][0] + b3v.x) * w4v.x;
        e += celu_f(acc3[mb][1] + b3v.y) * w4v.y;
        e += celu_f(acc3[mb][2] + b3v.z) * w4v.z;
        e += celu_f(acc3[mb][3] + b3v.w) * w4v.w;
    }
    if (tile * TM + w * 16 + lm >= NPS) e = 0.0f;   // mask padded atoms
    #pragma unroll
    for (int o = 32; o > 0; o >>= 1) e += __shfl_xor(e, o);

    float* red = (float*)&Ast[0][0][0][0];          // Ast dead (all waves past L1 via barrier)
    if (l == 0) red[w] = e;
    __syncthreads();
    if (t == 0) {
        int nv = NPS - tile * TM; if (nv > TM) nv = TM;
        partials[tile * (S_ * E_) + se] = red[0] + red[1] + red[2] + red[3] + (float)nv * b4[se];
    }
}

__global__ void reduce_partials(const float* __restrict__ p, int n, float* __restrict__ out)
{
    float s = 0.0f;
    for (int i = threadIdx.x; i < n; i += 256) s += p[i];
    #pragma unroll
    for (int o = 32; o > 0; o >>= 1) s += __shfl_xor(s, o);
    __shared__ float sm[4];
    if ((threadIdx.x & 63) == 0) sm[threadIdx.x >> 6] = s;
    __syncthreads();
    if (threadIdx.x == 0) out[0] = (sm[0] + sm[1] + sm[2] + sm[3]) * (1.0f / E_);
}

extern "C" void kernel_launch(void* const* d_in, const int* in_sizes, int n_in,
                              void* d_out, int out_size, void* d_ws, size_t ws_size,
                              hipStream_t stream)
{
    const float* aev = (const float*)d_in[0];
    const int*   idx = (const int*)  d_in[2];
    const float* W1  = (const float*)d_in[3];
    const float* b1  = (const float*)d_in[4];
    const float* W2  = (const float*)d_in[5];
    const float* b2  = (const float*)d_in[6];
    const float* W3  = (const float*)d_in[7];
    const float* b3  = (const float*)d_in[8];
    const float* W4  = (const float*)d_in[9];
    const float* b4  = (const float*)d_in[10];
    float* out = (float*)d_out;

    ushort* w1p = (ushort*)d_ws;
    ushort* w2p = w1p + (size_t)S_ * E_ * KB1 * NB1 * 512;
    ushort* w3p = w2p + (size_t)S_ * E_ * KB2 * NB2 * 512;
    float* partials = (float*)(w3p + (size_t)S_ * E_ * KB3 * NB3 * 512);

    pack_all<<<S_ * E_ * (KB1 + KB2 + KB3), 256, 0, stream>>>(W1, W2, W3, w1p, w2p, w3p);

    dim3 grid(32 * TG, NG);   // supertile: 8 tiles x 32 se per group; XCD=se%8
    ani_mfma<<<grid, 256, 0, stream>>>(aev, idx, w1p, w2p, w3p,
                                       b1, b2, b3, W4, b4, partials);
    reduce_partials<<<1, 256, 0, stream>>>(partials, NT * S_ * E_, out);
}